// Round 13
// baseline (272.275 us; speedup 1.0000x reference)
//
#include <hip/hip_runtime.h>

#define AW 264   // fp16 elems per act row stride (256 + 8 pad)
// Row swizzle: rows 8..15 shifted +16 halfs (32B) so bank-start
// (m16 + 2*(m16>>3) + q) mod 8 is exactly uniform across the wave.
#define ROW(m) ((m) * AW + (((m) >> 3) << 4))
#define YW 136   // f32 elems per Ys row (128 + 8 pad)

typedef _Float16 f16x8 __attribute__((ext_vector_type(8)));
typedef _Float16 f16x4 __attribute__((ext_vector_type(4)));
typedef __attribute__((ext_vector_type(4))) float f32x4;

// 5-op tanh: 1 - 2/(e^{2x}+1). Safe at +/-inf. |err| ~1e-7.
__device__ __forceinline__ float fast_tanh(float x) {
    float e = __expf(2.0f * x);
    return 1.0f - 2.0f / (e + 1.0f);
}
// Workgroup barrier ordering LDS only — does NOT drain vmcnt, so global
// loads issued before it stay in flight across it.
__device__ __forceinline__ void bar_lds() {
    asm volatile("s_waitcnt lgkmcnt(0)\n\ts_barrier" ::: "memory");
}

// ---------------- fused precompute: weights -> MFMA fragment layout, hi/lo fp16 ----
// F layout: [plane][nt][kc][lane(64)][j(8)]; value = W[n*K+k], n=nt*16+(l&15),
// k=kc*32+(l>>4)*8+j. Same lane formula serves as A- or B-operand fragment.
__global__ __launch_bounds__(256) void pk_all(
    const float* __restrict__ Wvf1, const float* __restrict__ Wvf2,
    const float* __restrict__ Wm,   const float* __restrict__ bm,
    const float* __restrict__ logsig,
    _Float16* __restrict__ W1F, _Float16* __restrict__ W2F,
    _Float16* __restrict__ A3F, float* __restrict__ c_all)
{
    __shared__ float ls[32][62];
    const int b = blockIdx.x, t = threadIdx.x;
    if (b < 128) {                      // W1: N=256 x K=128 (16 nt, 4 kc)
        int u = b * 256 + t;
        int j = u & 7, l = (u >> 3) & 63;
        int kc = (u >> 9) & 3, nt = (u >> 9) >> 2;
        int n = nt * 16 + (l & 15), k = kc * 32 + (l >> 4) * 8 + j;
        float w = Wvf1[n * 128 + k];
        _Float16 hi = (_Float16)w;
        W1F[u] = hi;
        W1F[32768 + u] = (_Float16)(w - (float)hi);
    } else if (b < 384) {               // W2: 256x256 (16 nt, 8 kc)
        int u = (b - 128) * 256 + t;
        int j = u & 7, l = (u >> 3) & 63;
        int kc = (u >> 9) & 7, nt = (u >> 9) >> 3;
        int n = nt * 16 + (l & 15), k = kc * 32 + (l >> 4) * 8 + j;
        float w = Wvf2[n * 256 + k];
        _Float16 hi = (_Float16)w;
        W2F[u] = hi;
        W2F[65536 + u] = (_Float16)(w - (float)hi);
    } else if (b < 896) {               // A_r, r-chunks of 8 (4 chunks x 128 blocks)
        for (int e2 = t; e2 < 32 * 62; e2 += 256)
            ls[e2 / 62][e2 % 62] = logsig[(e2 / 62) * 63 + 1 + (e2 % 62)];
        __syncthreads();
        int idx = b - 384;
        int chunk = idx >> 7;
        int u = (idx & 127) * 256 + t;
        int j = u & 7, l = (u >> 3) & 63, kc = (u >> 9) & 7, nt = (u >> 12) & 7;
        int h = nt * 16 + (l & 15);
        int v = kc * 32 + (l >> 4) * 8 + j;
        int r0 = chunk * 8;
        float acc[8];
#pragma unroll
        for (int r = 0; r < 8; r++) acc[r] = 0.f;
        for (int ll = 0; ll < 62; ll++) {
            float wv2 = Wm[(h * 62 + ll) * 256 + v];
#pragma unroll
            for (int r = 0; r < 8; r++) acc[r] += wv2 * ls[r0 + r][ll];
        }
        for (int r = 0; r < 8; r++) {
            _Float16 hi = (_Float16)acc[r];
            A3F[(r0 + r) * 65536 + u] = hi;
            A3F[(r0 + r) * 65536 + 32768 + u] = (_Float16)(acc[r] - (float)hi);
        }
    } else {                            // c_r[h] = bm[h,:] . seg_r
        int u = (b - 896) * 256 + t;
        int r = u >> 7, h = u & 127;
        float acc = 0.f;
        for (int ll = 0; ll < 62; ll++) acc += bm[h * 62 + ll] * logsig[r * 63 + 1 + ll];
        c_all[u] = acc;
    }
}

// ---------------- main fused kernel: 32 blocks x 16 rows, 8 waves, 20-step Heun ---
// W1 hi/lo resident in REGISTERS, loaded ONCE (r9 proved no-spill at this
// liveness). Per-eval stream = W2 + A_r windows only (384 KB/CU). Ping-pong
// hi/lo act buffers with bank-swizzled rows (conflict-free act reads).
// Transposed MFMA (weights = A-operand), fp16 hi/lo 3-chain (absmax 0.0039).
__global__ __launch_bounds__(512, 2) void rde_main(
    const float* __restrict__ ts, const float* __restrict__ x0,
    const float* __restrict__ intervals,
    const float* __restrict__ b1g, const float* __restrict__ b2g,
    const float* __restrict__ Win, const float* __restrict__ bin,
    const float* __restrict__ Wout, const float* __restrict__ bout,
    const _Float16* __restrict__ W1F, const _Float16* __restrict__ W2F,
    const _Float16* __restrict__ A3F, const float* __restrict__ c_all,
    float* __restrict__ out)
{
    __shared__ __align__(16) _Float16 P0h[16 * AW + 16], P0l[16 * AW + 16];
    __shared__ __align__(16) _Float16 P1h[16 * AW + 16], P1l[16 * AW + 16];
    __shared__ float Ys[16 * YW];
    __shared__ float ivl[33];
    __shared__ int   r_arr[40];
    __shared__ float s_arr[40];
    __shared__ float lg[16][12];

    const int t    = threadIdx.x;
    const int lane = t & 63;
    const int wv   = t >> 6;        // wave 0..7
    const int m16  = lane & 15;     // batch row within tile
    const int q    = lane >> 4;
    const int row0 = blockIdx.x * 16;

    if (t < 33) ivl[t] = intervals[t];
    __syncthreads();

    const float ts0 = ts[0];
    const float dt  = __fdiv_rn(ts[32] - ts0, 20.0f);   // bit-exact vs reference

    if (t < 40) {   // searchsorted idx + 1/delta for all 40 VF evals
        int i = t >> 1;
        float tv = ts0 + (float)i * dt;
        if (t & 1) tv += dt;
        int p = 0;
        for (int j2 = 0; j2 < 32; j2++) p += (ivl[1 + j2] < tv) ? 1 : 0;
        int idx = p + 1;
        idx = idx < 1 ? 1 : idx;
        idx = idx > 32 ? 32 : idx;
        r_arr[t] = idx - 1;
        s_arr[t] = __fdiv_rn(1.0f, ivl[idx] - ivl[idx - 1]);
    }

    // biases along D rows (q*4+r) for this wave's stage1/2 n-tiles wv*2, wv*2+1
    f32x4 b1f[2], b2f[2];
#pragma unroll
    for (int tt = 0; tt < 2; tt++) {
        b1f[tt] = *(const f32x4*)(b1g + (wv * 2 + tt) * 16 + q * 4);
        b2f[tt] = *(const f32x4*)(b2g + (wv * 2 + tt) * 16 + q * 4);
    }

    // W1 hi/lo fragments: loaded ONCE, resident for the whole kernel (64 regs).
    f16x8 w1f[2][4][2];
#pragma unroll
    for (int tt = 0; tt < 2; tt++)
#pragma unroll
        for (int kc = 0; kc < 4; kc++) {
            const _Float16* bp = W1F + (((wv * 2 + tt) * 4 + kc) * 64 + lane) * 8;
            w1f[tt][kc][0] = *(const f16x8*)bp;
            w1f[tt][kc][1] = *(const f16x8*)(bp + 32768);
        }

    // y0 = x0 @ Win.T + bin -> Y regs (stage3 D layout: rows q*4+r, col wv*16+m16)
    float Y[4], K1[4];
    {
        const float* xr = x0 + (row0 + m16) * 5;
        float xv[5];
#pragma unroll
        for (int d = 0; d < 5; d++) xv[d] = xr[d];
        int h0 = wv * 16 + q * 4;
        f16x4 hv, lv;
#pragma unroll
        for (int r = 0; r < 4; r++) {
            float acc = bin[h0 + r];
#pragma unroll
            for (int d = 0; d < 5; d++) acc += xv[d] * Win[(h0 + r) * 5 + d];
            Y[r] = acc;
            K1[r] = 0.f;
            _Float16 hi = (_Float16)acc;
            hv[r] = hi;
            lv[r] = (_Float16)(acc - (float)hi);
        }
        *(f16x4*)(P0h + ROW(m16) + h0) = hv;   // 512 thr x 4 = full 16x128 coverage
        *(f16x4*)(P0l + ROW(m16) + h0) = lv;
    }
    __syncthreads();

    _Float16 *Aih = P0h, *Ail = P0l;    // in buffers
    _Float16 *Aoh = P1h, *Aol = P1l;    // out buffers

#pragma unroll 1
    for (int e = 0; e < 40; e++) {
        const int half = e & 1;
        const int ri   = r_arr[e];
        const float s  = s_arr[e];
        const _Float16* ABase = A3F + ri * 65536;

        // ---- stage1: h1 = relu(W1 . y), K=128; W1 resident in regs ----
        // issue W2 window A (kc 0..3) first — in flight across all of stage1
        f16x8 w2a[2][4][2];
#pragma unroll
        for (int tt = 0; tt < 2; tt++)
#pragma unroll
            for (int kc = 0; kc < 4; kc++) {
                const _Float16* bp = W2F + (((wv * 2 + tt) * 8 + kc) * 64 + lane) * 8;
                w2a[tt][kc][0] = *(const f16x8*)bp;
                w2a[tt][kc][1] = *(const f16x8*)(bp + 65536);
            }
        f32x4 aA[2], aB[2], aC[2];
#pragma unroll
        for (int tt = 0; tt < 2; tt++) {
            aA[tt] = b1f[tt];
            aB[tt] = (f32x4){0.f, 0.f, 0.f, 0.f};
            aC[tt] = (f32x4){0.f, 0.f, 0.f, 0.f};
        }
#pragma unroll
        for (int kc = 0; kc < 4; kc++) {
            int ao = ROW(m16) + kc * 32 + q * 8;
            f16x8 ah = *(const f16x8*)(Aih + ao);
            f16x8 al = *(const f16x8*)(Ail + ao);
#pragma unroll
            for (int tt = 0; tt < 2; tt++) {
                aA[tt] = __builtin_amdgcn_mfma_f32_16x16x32_f16(w1f[tt][kc][0], ah, aA[tt], 0, 0, 0);
                aB[tt] = __builtin_amdgcn_mfma_f32_16x16x32_f16(w1f[tt][kc][1], ah, aB[tt], 0, 0, 0);
                aC[tt] = __builtin_amdgcn_mfma_f32_16x16x32_f16(w1f[tt][kc][0], al, aC[tt], 0, 0, 0);
            }
        }
#pragma unroll
        for (int tt = 0; tt < 2; tt++) {        // commit h1 -> out, packed b64 hi/lo
            int n0 = (wv * 2 + tt) * 16 + q * 4;
            f16x4 hv, lv;
#pragma unroll
            for (int r = 0; r < 4; r++) {       // D: col=lane&15 (m), row=q*4+r (n)
                float v = fmaxf(aA[tt][r] + aB[tt][r] + aC[tt][r], 0.f);
                _Float16 hi = (_Float16)v;
                hv[r] = hi;
                lv[r] = (_Float16)(v - (float)hi);
            }
            *(f16x4*)(Aoh + ROW(m16) + n0) = hv;
            *(f16x4*)(Aol + ROW(m16) + n0) = lv;
        }
        bar_lds();

        // ---- stage2: h2 = tanh(W2 . h1), K=256 ----
#pragma unroll
        for (int tt = 0; tt < 2; tt++) {
            aA[tt] = b2f[tt];
            aB[tt] = (f32x4){0.f, 0.f, 0.f, 0.f};
            aC[tt] = (f32x4){0.f, 0.f, 0.f, 0.f};
        }
#pragma unroll
        for (int kc = 0; kc < 4; kc++) {        // first half with window A
            int ao = ROW(m16) + kc * 32 + q * 8;
            f16x8 ah = *(const f16x8*)(Aoh + ao);
            f16x8 al = *(const f16x8*)(Aol + ao);
#pragma unroll
            for (int tt = 0; tt < 2; tt++) {
                aA[tt] = __builtin_amdgcn_mfma_f32_16x16x32_f16(w2a[tt][kc][0], ah, aA[tt], 0, 0, 0);
                aB[tt] = __builtin_amdgcn_mfma_f32_16x16x32_f16(w2a[tt][kc][1], ah, aB[tt], 0, 0, 0);
                aC[tt] = __builtin_amdgcn_mfma_f32_16x16x32_f16(w2a[tt][kc][0], al, aC[tt], 0, 0, 0);
            }
        }
        f16x8 w2b[2][4][2];                     // window B (kc 4..7)
#pragma unroll
        for (int tt = 0; tt < 2; tt++)
#pragma unroll
            for (int kc = 0; kc < 4; kc++) {
                const _Float16* bp = W2F + (((wv * 2 + tt) * 8 + 4 + kc) * 64 + lane) * 8;
                w2b[tt][kc][0] = *(const f16x8*)bp;
                w2b[tt][kc][1] = *(const f16x8*)(bp + 65536);
            }
#pragma unroll
        for (int kc = 0; kc < 4; kc++) {        // second half with window B
            int ao = ROW(m16) + (4 + kc) * 32 + q * 8;
            f16x8 ah = *(const f16x8*)(Aoh + ao);
            f16x8 al = *(const f16x8*)(Aol + ao);
#pragma unroll
            for (int tt = 0; tt < 2; tt++) {
                aA[tt] = __builtin_amdgcn_mfma_f32_16x16x32_f16(w2b[tt][kc][0], ah, aA[tt], 0, 0, 0);
                aB[tt] = __builtin_amdgcn_mfma_f32_16x16x32_f16(w2b[tt][kc][1], ah, aB[tt], 0, 0, 0);
                aC[tt] = __builtin_amdgcn_mfma_f32_16x16x32_f16(w2b[tt][kc][0], al, aC[tt], 0, 0, 0);
            }
        }
        // issue A_r window A (kc 0..3; stage3 n-tile = wv) + c vector
        f16x8 a3a[4][2];
#pragma unroll
        for (int kc = 0; kc < 4; kc++) {
            const _Float16* bp = ABase + ((wv * 8 + kc) * 64 + lane) * 8;
            a3a[kc][0] = *(const f16x8*)bp;
            a3a[kc][1] = *(const f16x8*)(bp + 32768);
        }
        f32x4 cf = *(const f32x4*)(c_all + ri * 128 + wv * 16 + q * 4);
#pragma unroll
        for (int tt = 0; tt < 2; tt++) {        // commit h2 (tanh) -> in, packed b64
            int n0 = (wv * 2 + tt) * 16 + q * 4;
            f16x4 hv, lv;
#pragma unroll
            for (int r = 0; r < 4; r++) {
                float v = fast_tanh(aA[tt][r] + aB[tt][r] + aC[tt][r]);
                _Float16 hi = (_Float16)v;
                hv[r] = hi;
                lv[r] = (_Float16)(v - (float)hi);
            }
            *(f16x4*)(Aih + ROW(m16) + n0) = hv;
            *(f16x4*)(Ail + ROW(m16) + n0) = lv;
        }
        bar_lds();

        // ---- stage3: k = (A_r . h2 + c) * s; window B issued here ----
        f16x8 a3b[4][2];                        // kc 4..7
#pragma unroll
        for (int kc = 0; kc < 4; kc++) {
            const _Float16* bp = ABase + ((wv * 8 + 4 + kc) * 64 + lane) * 8;
            a3b[kc][0] = *(const f16x8*)bp;
            a3b[kc][1] = *(const f16x8*)(bp + 32768);
        }
        f32x4 kA = cf;
        f32x4 kB = (f32x4){0.f, 0.f, 0.f, 0.f};
        f32x4 kC = (f32x4){0.f, 0.f, 0.f, 0.f};
#pragma unroll
        for (int kc = 0; kc < 4; kc++) {        // kc 0..3 with a3a
            int ao = ROW(m16) + kc * 32 + q * 8;
            f16x8 ah = *(const f16x8*)(Aih + ao);
            f16x8 al = *(const f16x8*)(Ail + ao);
            kA = __builtin_amdgcn_mfma_f32_16x16x32_f16(a3a[kc][0], ah, kA, 0, 0, 0);
            kB = __builtin_amdgcn_mfma_f32_16x16x32_f16(a3a[kc][1], ah, kB, 0, 0, 0);
            kC = __builtin_amdgcn_mfma_f32_16x16x32_f16(a3a[kc][0], al, kC, 0, 0, 0);
        }
#pragma unroll
        for (int kc = 0; kc < 4; kc++) {        // kc 4..7 with a3b
            int ao = ROW(m16) + (4 + kc) * 32 + q * 8;
            f16x8 ah = *(const f16x8*)(Aih + ao);
            f16x8 al = *(const f16x8*)(Ail + ao);
            kA = __builtin_amdgcn_mfma_f32_16x16x32_f16(a3b[kc][0], ah, kA, 0, 0, 0);
            kB = __builtin_amdgcn_mfma_f32_16x16x32_f16(a3b[kc][1], ah, kB, 0, 0, 0);
            kC = __builtin_amdgcn_mfma_f32_16x16x32_f16(a3b[kc][0], al, kC, 0, 0, 0);
        }
        {                                       // Heun commit + y -> out, packed b64
            int h0 = wv * 16 + q * 4;
            f16x4 hv, lv;
#pragma unroll
            for (int r = 0; r < 4; r++) {
                float kv = (kA[r] + kB[r] + kC[r]) * s;
                float yn;
                if (half == 0) {                 // k1: stash, form y+dt*k1
                    K1[r] = kv;
                    yn = Y[r] + dt * kv;
                } else {                         // k2: y += 0.5*dt*(k1+k2)
                    yn = Y[r] + 0.5f * dt * (K1[r] + kv);
                    Y[r] = yn;
                }
                _Float16 hi = (_Float16)yn;
                hv[r] = hi;
                lv[r] = (_Float16)(yn - (float)hi);
            }
            *(f16x4*)(Aoh + ROW(m16) + h0) = hv;
            *(f16x4*)(Aol + ROW(m16) + h0) = lv;
        }
        bar_lds();
        _Float16* tp;
        tp = Aih; Aih = Aoh; Aoh = tp;
        tp = Ail; Ail = Aol; Aol = tp;
    }

    // epilogue: Y regs -> Ys f32 [m][h]
#pragma unroll
    for (int r = 0; r < 4; r++)
        Ys[m16 * YW + wv * 16 + q * 4 + r] = Y[r];
    __syncthreads();
    if (t < 160) {                  // logits
        int m = t / 10, c = t % 10;
        float acc = bout[c];
        for (int k = 0; k < 128; k++) acc += Ys[m * YW + k] * Wout[c * 128 + k];
        lg[m][c] = acc;
    }
    __syncthreads();
    if (t < 16) {                   // softmax
        float mx = -1e30f;
#pragma unroll
        for (int c = 0; c < 10; c++) mx = fmaxf(mx, lg[t][c]);
        float ex[10], sum = 0.f;
#pragma unroll
        for (int c = 0; c < 10; c++) { ex[c] = expf(lg[t][c] - mx); sum += ex[c]; }
        float inv = __fdiv_rn(1.0f, sum);
#pragma unroll
        for (int c = 0; c < 10; c++) out[(row0 + t) * 10 + c] = ex[c] * inv;
    }
}

extern "C" void kernel_launch(void* const* d_in, const int* in_sizes, int n_in,
                              void* d_out, int out_size, void* d_ws, size_t ws_size,
                              hipStream_t stream) {
    const float* ts     = (const float*)d_in[0];
    const float* logsig = (const float*)d_in[1];
    const float* x0     = (const float*)d_in[2];
    const float* ivls   = (const float*)d_in[3];
    const float* Wvf1   = (const float*)d_in[4];
    const float* bvf1   = (const float*)d_in[5];
    const float* Wvf2   = (const float*)d_in[6];
    const float* bvf2   = (const float*)d_in[7];
    const float* Wm     = (const float*)d_in[8];
    const float* bm     = (const float*)d_in[9];
    const float* Win    = (const float*)d_in[10];
    const float* bin    = (const float*)d_in[11];
    const float* Wout   = (const float*)d_in[12];
    const float* bout   = (const float*)d_in[13];

    _Float16* W1F = (_Float16*)d_ws;            // 65536 halfs (128KB, hi+lo)
    _Float16* W2F = W1F + 65536;                // 131072 halfs (256KB, hi+lo)
    _Float16* A3F = W2F + 131072;               // 32*65536 halfs (4MB, hi+lo per r)
    float* c_all = (float*)(A3F + 32 * 65536);  // 4096 f32 (16KB)
    float* out = (float*)d_out;

    pk_all<<<dim3(912), dim3(256), 0, stream>>>(Wvf1, Wvf2, Wm, bm, logsig,
                                                W1F, W2F, A3F, c_all);
    rde_main<<<dim3(32), dim3(512), 0, stream>>>(
        ts, x0, ivls, bvf1, bvf2, Win, bin, Wout, bout,
        W1F, W2F, A3F, c_all, out);
}